// Round 2
// baseline (798.776 us; speedup 1.0000x reference)
//
#include <hip/hip_runtime.h>
#include <math.h>

// (B, F, T, K) = (4096, 2048, 16, 8)
// logits[b,t,k] = sum_f h[b,f,t] * W[k,t,f] + bias[k,t]; out = sigmoid(logits), [B,T,K]
#define B_TOT 4096
#define F_DIM 2048
#define T_DIM 16
#define K_DIM 8
#define NB    4            // batches per workgroup
#define SF    64           // f-columns per tile
#define NSUP  (F_DIM / SF) // 32 tiles

// Thread partition: tp = tid&7 (t-pair, t = 2*tp+ts), fp = tid>>3 (f-pair, f = sc*64+2*fp+d).
// Each thread owns ALL K for its (t,f) slice -> every W[k][t][f] is read by exactly ONE
// thread per WG. So W goes global->register directly (L2-hot, 1 MiB total); LDS staging
// would not reduce traffic, and dropping it removes ALL main-loop barriers (the round-1
// bottleneck: 64 barriers x vmcnt(0) drain serialized the h stream to ~1.5 TB/s).

__global__ __launch_bounds__(256)
void ta_kernel(const float* __restrict__ h, const float* __restrict__ W,
               const float* __restrict__ bias, float* __restrict__ out)
{
    __shared__ float smem[8192];   // 32 KB, epilogue reduction only

    const int tid = threadIdx.x;
    const int tp  = tid & 7;
    const int fp  = tid >> 3;
    const int b0  = blockIdx.x * NB;

    float acc[NB][2][K_DIM];
#pragma unroll
    for (int nb = 0; nb < NB; ++nb)
#pragma unroll
        for (int ts = 0; ts < 2; ++ts)
#pragma unroll
            for (int k = 0; k < K_DIM; ++k) acc[nb][ts][k] = 0.f;

    // h as float2 along T: idx = b*16384 + f*8 + tp. Per-wave: 8 fp-groups x 8 tp ->
    // 64B fully-used sectors; d=0/1 pair completes each 128B line.
    const float2* h2 = (const float2*)h;
    unsigned ho[NB];
#pragma unroll
    for (int nb = 0; nb < NB; ++nb)
        ho[nb] = (unsigned)(b0 + nb) * 16384u + (unsigned)(fp * 16 + tp);

    // W float2 at (k, t=2tp+ts, f=2fp): float idx = k*32768 + t*2048 + sc*64 + 2*fp
    unsigned wo[2];
#pragma unroll
    for (int ts = 0; ts < 2; ++ts)
        wo[ts] = (unsigned)((2 * tp + ts) * 2048 + 2 * fp);

    // Named register double-buffers (all indices compile-time; rule #20)
    float2 hA[2 * NB], hB[2 * NB];         // [nb*2 + d]
    float2 wA[2 * K_DIM], wB[2 * K_DIM];   // [k*2 + ts]

    auto LH = [&](float2 (&buf)[2 * NB], int sc) {
#pragma unroll
        for (int nb = 0; nb < NB; ++nb)
#pragma unroll
            for (int d = 0; d < 2; ++d)
                buf[nb * 2 + d] = h2[ho[nb] + (unsigned)(sc * 512 + d * 8)];
    };
    auto LW = [&](float2 (&buf)[2 * K_DIM], int sc) {
#pragma unroll
        for (int k = 0; k < K_DIM; ++k)
#pragma unroll
            for (int ts = 0; ts < 2; ++ts)
                buf[k * 2 + ts] = *(const float2*)(W + k * 32768 + (int)wo[ts] + sc * 64);
    };
    auto DO_FMA = [&](float2 (&hv)[2 * NB], float2 (&wv)[2 * K_DIM]) {
#pragma unroll
        for (int k = 0; k < K_DIM; ++k)
#pragma unroll
            for (int ts = 0; ts < 2; ++ts)
#pragma unroll
                for (int nb = 0; nb < NB; ++nb) {
                    const float h0 = ts ? hv[nb * 2 + 0].y : hv[nb * 2 + 0].x;
                    const float h1 = ts ? hv[nb * 2 + 1].y : hv[nb * 2 + 1].x;
                    acc[nb][ts][k] = fmaf(h0, wv[k * 2 + ts].x, acc[nb][ts][k]);
                    acc[nb][ts][k] = fmaf(h1, wv[k * 2 + ts].y, acc[nb][ts][k]);
                }
    };

    // Barrier-free main loop: prefetch tile n+1 while computing tile n.
    LH(hA, 0); LW(wA, 0);
    for (int sc = 0; sc < NSUP; sc += 2) {
        LH(hB, sc + 1); LW(wB, sc + 1);    // issue next-tile loads first
        DO_FMA(hA, wA);
        if (sc + 2 < NSUP) { LH(hA, sc + 2); LW(wA, sc + 2); }
        DO_FMA(hB, wB);
    }

    // ---- epilogue: reduce 32 fp-partials per (nb,t,k); two 32KB chunks ----
    // writer banks: (fp + 4*tp)&31 -> 2 lanes/bank (free); reader: (tid+j)&31 -> 2/bank.
#pragma unroll
    for (int c = 0; c < 2; ++c) {
        __syncthreads();           // chunk c=1: previous chunk fully read
#pragma unroll
        for (int nbl = 0; nbl < 2; ++nbl)
#pragma unroll
            for (int ts = 0; ts < 2; ++ts) {
                const int t = 2 * tp + ts;
#pragma unroll
                for (int k = 0; k < K_DIM; ++k)
                    smem[(nbl * 16 + t) * 256 + k * 32 + ((fp + tp * 4) & 31)]
                        = acc[c * 2 + nbl][ts][k];
            }
        __syncthreads();
        const int nbl = tid >> 7, rem = tid & 127, tt = rem >> 3, kk = rem & 7;
        float s = 0.f;
#pragma unroll
        for (int j = 0; j < 32; ++j)
            s += smem[(nbl * 16 + tt) * 256 + kk * 32 + ((tid + j) & 31)];
        s += bias[kk * T_DIM + tt];
        s = 1.0f / (1.0f + __expf(-s));
        out[(size_t)(b0 + c * 2 + nbl) * (T_DIM * K_DIM) + rem] = s;
    }
}

extern "C" void kernel_launch(void* const* d_in, const int* in_sizes, int n_in,
                              void* d_out, int out_size, void* d_ws, size_t ws_size,
                              hipStream_t stream) {
    const float* h    = (const float*)d_in[0];   // [B, F, T] fp32
    const float* W    = (const float*)d_in[1];   // [K, T, F] fp32
    const float* bias = (const float*)d_in[2];   // [K, T] fp32
    float* out = (float*)d_out;                  // [B, T, K] fp32
    ta_kernel<<<dim3(B_TOT / NB), dim3(256), 0, stream>>>(h, W, bias, out);
}

// Round 3
// 732.810 us; speedup vs baseline: 1.0900x; 1.0900x over previous
//
#include <hip/hip_runtime.h>
#include <math.h>

// (B, F, T, K) = (4096, 2048, 16, 8)
// logits[b,t,k] = sum_f h[b,f,t] * W[k,t,f] + bias[k,t]; out = sigmoid(logits), [B,T,K]
#define B_TOT 4096
#define F_DIM 2048
#define T_DIM 16
#define K_DIM 8
#define NB    4            // batches per workgroup
#define SF    64           // f-columns per tile (16 per wave, wave-private)
#define NSUP  (F_DIM / SF) // 32 tiles

// Direct global->LDS DMA: dest = wave-uniform base + lane*16 (linear, rule #21);
// SOURCE is per-lane -> arbitrary 16B-granular gather, used here to pre-swizzle.
__device__ __forceinline__ void gload_lds16(const float* g, float* l) {
    __builtin_amdgcn_global_load_lds(
        (const __attribute__((address_space(1))) void*)g,
        (__attribute__((address_space(3))) void*)l,
        16, 0, 0);
}

// Zero main-loop barriers: wave w stages ONLY the f-slice it reads
// (f = sc*64 + w*16 + fl, fl 0..15), so stage->read is same-wave and a counted
// per-wave s_waitcnt vmcnt(16) replaces __syncthreads (which drained vmcnt(0)
// and serialized the h stream -- the round-0/1 bottleneck).
//
// Wave-private tile layout (2048 floats per buf), per k-region of 256 words:
//   word w = (t&1)*128 + (fl>>2)*32 + (t>>1)*4 + (fl&3)
// - DMA dest word = lane*4+c  => per-lane source = W[k][(lane&7)*2+(lane>>5)]
//   [f0 + ((lane>>3)&3)*4 + c], c=0..3 contiguous 16B ✓
// - ds_read bank = w&31 = tp*4 + (fr&3): 64 lanes -> 32 banks x2 = conflict-free.

__global__ __launch_bounds__(256)
void ta_kernel(const float* __restrict__ h, const float* __restrict__ W,
               const float* __restrict__ bias, float* __restrict__ out)
{
    __shared__ float smem[16384];   // [4 waves][2 bufs][2048]; epilogue reuses [0..8191]

    const int tid  = threadIdx.x;
    const int lane = tid & 63;
    const int wid  = tid >> 6;
    const int tp   = tid & 7;         // t = 2*tp + ts
    const int frl  = (tid >> 3) & 7;  // wave-local f residue
    const int b0   = blockIdx.x * NB;

    float* const wbuf0 = smem + wid * 4096;
    float* const wbuf1 = wbuf0 + 2048;

    float acc[NB][2][K_DIM];
#pragma unroll
    for (int nb = 0; nb < NB; ++nb)
#pragma unroll
        for (int ts = 0; ts < 2; ++ts)
#pragma unroll
            for (int k = 0; k < K_DIM; ++k) acc[nb][ts][k] = 0.f;

    // staging: lane's 16B source chunk (t, f-base) from dest-word inversion
    const int tl  = (lane & 7) * 2 + (lane >> 5);
    const int flb = ((lane >> 3) & 3) * 4;
    const float* const wsrc = W + tl * F_DIM + wid * 16 + flb;  // + k*32768 + sc*64
    float* const ldst0 = wbuf0 + lane * 4;                      // + k*256
    float* const ldst1 = wbuf1 + lane * 4;

    // ds_read word offsets within wave buf (compile-time il/ts, k adds k*256)
    int rdo[2][2];
#pragma unroll
    for (int il = 0; il < 2; ++il)
#pragma unroll
        for (int ts = 0; ts < 2; ++ts)
            rdo[il][ts] = ts * 128 + (il * 2 + (frl >> 2)) * 32 + tp * 4 + (frl & 3);

    // h float2 idx = b*16384 + f*8 + tp, f = sc*64 + wid*16 + il*8 + frl
    // wave lanes (frl,tp) -> 512B contiguous per load instruction.
    const float2* const hb =
        (const float2*)h + (size_t)b0 * 16384 + wid * 128 + frl * 8 + tp;

    float2 hA[2 * NB], hB[2 * NB];   // [nb*2 + il], named ping-pong (rule #20)

    auto LH = [&](float2 (&buf)[2 * NB], int sc) {
#pragma unroll
        for (int nb = 0; nb < NB; ++nb)
#pragma unroll
            for (int il = 0; il < 2; ++il)
                buf[nb * 2 + il] = hb[nb * 16384 + sc * 512 + il * 64];
    };
    auto STAGE = [&](float* ldst, int sc) {
#pragma unroll
        for (int k = 0; k < K_DIM; ++k)
            gload_lds16(wsrc + k * (T_DIM * F_DIM) + sc * SF, ldst + k * 256);
    };
    auto COMP = [&](const float* sm, float2 (&hv)[2 * NB]) {
#pragma unroll
        for (int il = 0; il < 2; ++il)
#pragma unroll
            for (int ts = 0; ts < 2; ++ts) {
                float wv[K_DIM];
#pragma unroll
                for (int k = 0; k < K_DIM; ++k)
                    wv[k] = sm[k * 256 + rdo[il][ts]];
#pragma unroll
                for (int nb = 0; nb < NB; ++nb) {
                    const float hx = ts ? hv[nb * 2 + il].y : hv[nb * 2 + il].x;
#pragma unroll
                    for (int k = 0; k < K_DIM; ++k)
                        acc[nb][ts][k] = fmaf(hx, wv[k], acc[nb][ts][k]);
                }
            }
    };

    // Prologue: tile 0 in flight
    LH(hA, 0);
    STAGE(ldst0, 0);

    // Per tile: issue next tile's 16 loads, then wait ONLY current tile
    // (vmcnt(16) = leave the 16 just-issued in flight; never drain to 0).
#define ITERX(sc, LDNXT, HCUR, HNXT, SMCUR)                        \
    do {                                                           \
        LH(HNXT, (sc) + 1);                                        \
        STAGE(LDNXT, (sc) + 1);                                    \
        asm volatile("s_waitcnt vmcnt(16)" ::: "memory");          \
        __builtin_amdgcn_sched_barrier(0);                         \
        COMP(SMCUR, HCUR);                                         \
    } while (0)

#pragma unroll 1
    for (int p = 0; p < 15; ++p) {     // tiles 0..29 as named ping-pong pairs
        ITERX(2 * p,     ldst1, hA, hB, wbuf0);
        ITERX(2 * p + 1, ldst0, hB, hA, wbuf1);
    }
    ITERX(30, ldst1, hA, hB, wbuf0);
    asm volatile("s_waitcnt vmcnt(0)" ::: "memory");   // tail: drain tile 31
    __builtin_amdgcn_sched_barrier(0);
    COMP(wbuf1, hB);
#undef ITERX

    // ---- epilogue: reduce 32 partials (wid*8+frl = tid>>3) per (nb,t,k) ----
    // Only 2 barriers in the whole kernel. Banks: writer (fp+4tp)&31, reader
    // (tid+j)&31 -- both 2-way max (free). Proven in rounds 0-2.
    const int fp = tid >> 3;
#pragma unroll
    for (int c = 0; c < 2; ++c) {
        __syncthreads();
#pragma unroll
        for (int nbl = 0; nbl < 2; ++nbl)
#pragma unroll
            for (int ts = 0; ts < 2; ++ts) {
                const int t = 2 * tp + ts;
#pragma unroll
                for (int k = 0; k < K_DIM; ++k)
                    smem[(nbl * 16 + t) * 256 + k * 32 + ((fp + tp * 4) & 31)]
                        = acc[c * 2 + nbl][ts][k];
            }
        __syncthreads();
        const int nbl = tid >> 7, rem = tid & 127, tt = rem >> 3, kk = rem & 7;
        float s = 0.f;
#pragma unroll
        for (int j = 0; j < 32; ++j)
            s += smem[(nbl * 16 + tt) * 256 + kk * 32 + ((tid + j) & 31)];
        s += bias[kk * T_DIM + tt];
        s = 1.0f / (1.0f + __expf(-s));
        out[(size_t)(b0 + c * 2 + nbl) * (T_DIM * K_DIM) + rem] = s;
    }
}

extern "C" void kernel_launch(void* const* d_in, const int* in_sizes, int n_in,
                              void* d_out, int out_size, void* d_ws, size_t ws_size,
                              hipStream_t stream) {
    const float* h    = (const float*)d_in[0];   // [B, F, T] fp32
    const float* W    = (const float*)d_in[1];   // [K, T, F] fp32
    const float* bias = (const float*)d_in[2];   // [K, T] fp32
    float* out = (float*)d_out;                  // [B, T, K] fp32
    ta_kernel<<<dim3(B_TOT / NB), dim3(256), 0, stream>>>(h, W, bias, out);
}